// Round 22
// baseline (258.018 us; speedup 1.0000x reference)
//
#include <hip/hip_runtime.h>
#include <cstdint>
#include <cstddef>

typedef __bf16 bf16;
typedef __attribute__((ext_vector_type(8))) __bf16 bf16x8;
typedef __attribute__((ext_vector_type(4))) __bf16 bf16x4;
typedef __attribute__((ext_vector_type(4))) float f32x4;

#define MFMA16 __builtin_amdgcn_mfma_f32_16x16x32_bf16

// async global -> LDS, 16B per lane. LDS dest is base + lane*16.
__device__ __forceinline__ void gload16(const bf16* g, bf16* l) {
    __builtin_amdgcn_global_load_lds(
        (const __attribute__((address_space(1))) uint32_t*)g,
        (__attribute__((address_space(3))) uint32_t*)l, 16, 0, 0);
}

// pack two f32 -> u32 of 2 bf16 (elem0 = lo bits)
__device__ __forceinline__ unsigned pk2(float lo, float hi) {
    union { bf16 h[2]; unsigned u; } c;
    c.h[0] = (bf16)lo; c.h[1] = (bf16)hi;
    return c.u;
}
// raw v_exp_f32: 2^x
__device__ __forceinline__ float fexp2(float x) {
    float r;
    asm("v_exp_f32 %0, %1" : "=v"(r) : "v"(x));
    return r;
}

// bijective XCD chunk swizzle (nwg % 8 == 0)
__device__ __forceinline__ int xcd_swz(int id, int nwg) {
    return (id & 7) * (nwg >> 3) + (id >> 3);
}

#define SBAR()  __builtin_amdgcn_s_barrier()
#define SCHED() __builtin_amdgcn_sched_barrier(0)

// ---------------------------------------------------------------------------
// Fused weight prep: all 6 transposes+casts in ONE launch.
// ---------------------------------------------------------------------------
__global__ __launch_bounds__(256) void transpose_all(
    const float* __restrict__ wq, const float* __restrict__ wk,
    const float* __restrict__ wv, const float* __restrict__ wo,
    const float* __restrict__ w0, const float* __restrict__ w1,
    bf16* __restrict__ Wqkv, bf16* __restrict__ Wot,
    bf16* __restrict__ W0t, bf16* __restrict__ W1t)
{
    __shared__ float t[32][33];
    const int b = blockIdx.x;
    const float* src;
    bf16* dst;
    int K, N, tt;
    if (b < 1024)      { src = wq; dst = Wqkv;                       K = 1024; N = 1024; tt = b; }
    else if (b < 2048) { src = wk; dst = Wqkv + (size_t)1024 * 1024; K = 1024; N = 1024; tt = b - 1024; }
    else if (b < 3072) { src = wv; dst = Wqkv + (size_t)2048 * 1024; K = 1024; N = 1024; tt = b - 2048; }
    else if (b < 4096) { src = wo; dst = Wot;                        K = 1024; N = 1024; tt = b - 3072; }
    else if (b < 8192) { src = w0; dst = W0t;                        K = 1024; N = 4096; tt = b - 4096; }
    else               { src = w1; dst = W1t;                        K = 4096; N = 1024; tt = b - 8192; }
    const int ntx = N >> 5;
    const int n0 = (tt % ntx) * 32, k0 = (tt / ntx) * 32;
    const int tx = threadIdx.x, ty = threadIdx.y;
    #pragma unroll
    for (int i = ty; i < 32; i += 8)
        t[i][tx] = src[(size_t)(k0 + i) * N + n0 + tx];
    __syncthreads();
    #pragma unroll
    for (int i = ty; i < 32; i += 8)
        dst[(size_t)(n0 + i) * K + k0 + tx] = (bf16)t[tx][i];
}

// ---------------------------------------------------------------------------
// Batched bf16 transpose for V: src [Z][2048][64] -> dst [Z][64][2048]
// ---------------------------------------------------------------------------
__global__ __launch_bounds__(256) void transpose_v(
    const bf16* __restrict__ src, bf16* __restrict__ dst)
{
    __shared__ bf16 t[32][33];
    const int z = blockIdx.z;
    const int h0 = blockIdx.x * 32, s0 = blockIdx.y * 32;
    const bf16* sp = src + (size_t)z * 2048 * 64;
    bf16* dp = dst + (size_t)z * 64 * 2048;
    const int tx = threadIdx.x, ty = threadIdx.y;
    #pragma unroll
    for (int i = ty; i < 32; i += 8)
        t[i][tx] = sp[(size_t)(s0 + i) * 64 + h0 + tx];
    __syncthreads();
    #pragma unroll
    for (int i = ty; i < 32; i += 8)
        dp[(size_t)(h0 + i) * 2048 + s0 + tx] = t[tx][i];
}

// ---------------------------------------------------------------------------
// LayerNorm (D=1024) fp32 in -> bf16 out. One block (256 thr) per row.
// ---------------------------------------------------------------------------
__global__ __launch_bounds__(256) void ln_kernel(
    const float* __restrict__ x, const float* __restrict__ sc,
    const float* __restrict__ bi, bf16* __restrict__ y)
{
    const int row = blockIdx.x, tid = threadIdx.x;
    const f32x4 v = ((const f32x4*)(x + (size_t)row * 1024))[tid];
    float s  = v[0] + v[1] + v[2] + v[3];
    float s2 = v[0]*v[0] + v[1]*v[1] + v[2]*v[2] + v[3]*v[3];
    #pragma unroll
    for (int d = 1; d < 64; d <<= 1) {
        s  += __shfl_xor(s, d);
        s2 += __shfl_xor(s2, d);
    }
    __shared__ float red[8];
    if ((tid & 63) == 0) { red[tid >> 6] = s; red[4 + (tid >> 6)] = s2; }
    __syncthreads();
    s  = red[0] + red[1] + red[2] + red[3];
    s2 = red[4] + red[5] + red[6] + red[7];
    const float mu = s * (1.f / 1024.f);
    const float rstd = rsqrtf(s2 * (1.f / 1024.f) - mu * mu + 1e-6f);
    const f32x4 s4 = ((const f32x4*)sc)[tid];
    const f32x4 b4 = ((const f32x4*)bi)[tid];
    bf16x4 o;
    #pragma unroll
    for (int j = 0; j < 4; ++j)
        o[j] = (bf16)((v[j] - mu) * rstd * s4[j] + b4[j]);
    ((bf16x4*)(y + (size_t)row * 1024))[tid] = o;
}

// ---------------------------------------------------------------------------
// bf16 GEMM (R20/R21-validated), BK=64, 3-bit both-sides XOR swizzle:
//  DBUF=false: SINGLE-buffered LDS + TLP. DBUF=true: dbuf + counted vmcnt.
// Tiles: 128x128 (32KB), 64x64 (16KB -> high blocks/CU, grid permitting).
// EPI 0: QKV scatter (+bias; Q pre-scaled by 0.125*log2e), [Z][T][H] x3.
// EPI 1: fp32 out = acc + bias + res. EPI 2: bf16 gelu(acc + bias).
// ---------------------------------------------------------------------------
template <int EPI, int BM, int BN, int NW, bool DBUF>
__global__ __launch_bounds__(NW * 64, 2) void gemm_kernel(
    const bf16* __restrict__ A, const bf16* __restrict__ Bt,
    int M, int N, int K,
    const float* __restrict__ b0, const float* __restrict__ b1,
    const float* __restrict__ b2, const float* __restrict__ res,
    bf16* __restrict__ o0, bf16* __restrict__ o1, bf16* __restrict__ o2,
    float* __restrict__ of)
{
    constexpr int NRW    = NW / 2;
    constexpr int MR     = BM / 32;
    constexpr int NR     = BN / 16 / NRW;
    constexpr int ACALLS = BM / (8 * NW);
    constexpr int BCALLS = BN / (8 * NW);
    constexpr int NLOADS = ACALLS + BCALLS;
    constexpr int NBUF   = DBUF ? 2 : 1;
    static_assert(NLOADS == 8 || NLOADS == 6 || NLOADS == 4, "vmcnt literal");
    __shared__ bf16 As[NBUF][BM * 64];
    __shared__ bf16 Bs[NBUF][BN * 64];

    const int tid = threadIdx.x;
    const int wave = tid >> 6, lane = tid & 63;
    const int wr = (wave / NRW) * (MR * 16), wc = (wave % NRW) * (NR * 16);
    const int lr = lane & 15, lg = lane >> 4;

    const int nwg = gridDim.x * gridDim.y;
    const int id = xcd_swz(blockIdx.y * gridDim.x + blockIdx.x, nwg);
    const int bm = (id / gridDim.x) * BM, bn = (id % gridDim.x) * BN;

    f32x4 acc[MR][NR] = {};

    const int srow = tid >> 3;
    const int scol = (((tid & 7) ^ ((tid >> 3) & 7)) * 8);
    const bf16* Ag = A  + (size_t)(bm + srow) * K + scol;
    const bf16* Bg = Bt + (size_t)(bn + srow) * K + scol;

    auto stage = [&](int buf, int k0) {
        #pragma unroll
        for (int c = 0; c < ACALLS; ++c)
            gload16(Ag + (size_t)(c * 8 * NW) * K + k0,
                    &As[buf][(c * 8 * NW) * 64] + (size_t)tid * 8);
        #pragma unroll
        for (int c = 0; c < BCALLS; ++c)
            gload16(Bg + (size_t)(c * 8 * NW) * K + k0,
                    &Bs[buf][(c * 8 * NW) * 64] + (size_t)tid * 8);
    };

    const int f3 = lane & 7;
    const int ko0 = ((0 + lg) ^ f3) * 8;     // kh = 0
    const int ko1 = ((4 + lg) ^ f3) * 8;     // kh = 1

    auto mfma_tile = [&](int buf) {
        #pragma unroll
        for (int kh = 0; kh < 2; ++kh) {
            const int ko = kh ? ko1 : ko0;
            bf16x8 a[MR], b[NR];
            #pragma unroll
            for (int m = 0; m < MR; ++m)
                a[m] = *(const bf16x8*)&As[buf][(wr + m * 16 + lr) * 64 + ko];
            #pragma unroll
            for (int n = 0; n < NR; ++n)
                b[n] = *(const bf16x8*)&Bs[buf][(wc + n * 16 + lr) * 64 + ko];
            #pragma unroll
            for (int m = 0; m < MR; ++m)
                #pragma unroll
                for (int n = 0; n < NR; ++n)
                    acc[m][n] = MFMA16(a[m], b[n], acc[m][n], 0, 0, 0);
        }
    };

    const int nk = K >> 6;
    if constexpr (!DBUF) {
        for (int i = 0; i < nk; ++i) {
            stage(0, i << 6);
            __syncthreads();
            mfma_tile(0);
            __syncthreads();
        }
    } else {
        stage(0, 0);
        __syncthreads();
        int cur = 0;
        for (int i = 0; i < nk; ++i) {
            if (i + 1 < nk) {
                stage(cur ^ 1, (i + 1) << 6);
                SCHED();
                if constexpr (NLOADS == 8)
                    asm volatile("s_waitcnt vmcnt(8)" ::: "memory");
                else if constexpr (NLOADS == 6)
                    asm volatile("s_waitcnt vmcnt(6)" ::: "memory");
                else
                    asm volatile("s_waitcnt vmcnt(4)" ::: "memory");
            } else {
                asm volatile("s_waitcnt vmcnt(0)" ::: "memory");
            }
            SCHED();
            SBAR();
            SCHED();
            mfma_tile(cur);
            SCHED();
            asm volatile("s_waitcnt lgkmcnt(0)" ::: "memory");
            SCHED();
            SBAR();
            SCHED();
            cur ^= 1;
        }
    }

    const int rbase = bm + wr + (lg << 2);
    const int cbase = bn + wc + lr;
    #pragma unroll
    for (int m = 0; m < MR; ++m) {
        #pragma unroll
        for (int n = 0; n < NR; ++n) {
            const f32x4 v = acc[m][n];
            #pragma unroll
            for (int r = 0; r < 4; ++r) {
                const int row = rbase + m * 16 + r;
                const int col = cbase + n * 16;
                const float val = v[r];
                if constexpr (EPI == 0) {
                    const int which = col >> 10, cc = col & 1023;
                    const float* bp = (which == 0) ? b0 : (which == 1) ? b1 : b2;
                    bf16* dp = (which == 0) ? o0 : (which == 1) ? o1 : o2;
                    const float scl = (which == 0) ? 0.18033688011112042f : 1.0f;
                    const int bb = row >> 11, t = row & 2047;
                    const int nh = cc >> 6, hh = cc & 63;
                    dp[(((size_t)(bb * 16 + nh) * 2048 + t) << 6) + hh] =
                        (bf16)((val + bp[cc]) * scl);
                } else if constexpr (EPI == 1) {
                    of[(size_t)row * N + col] =
                        val + b0[col] + res[(size_t)row * N + col];
                } else {
                    const float xg = val + b0[col];
                    const float z2 = 1.5957691216f * (xg + 0.044715f * xg * xg * xg);
                    o0[(size_t)row * N + col] = (bf16)(xg / (1.f + __expf(-z2)));
                }
            }
        }
    }
}

// ---------------------------------------------------------------------------
// Flash attention (R21-validated, unchanged): fixed-m softmax (P = 2^s,
// no max tracking -- exp2-domain scores bounded ~2^26, scale cancels in
// O/l), 8 waves / 2 Q-tiles per block, shared K/V staging, swapped-QK^T,
// sigma-permuted V, l-via-ones-MFMA, direct-Q. Grid: 512 blocks.
// ---------------------------------------------------------------------------
__global__ __launch_bounds__(512) void attn_kernel(
    const bf16* __restrict__ q, const bf16* __restrict__ k,
    const bf16* __restrict__ vt, bf16* __restrict__ enc)
{
    __shared__ bf16 Ks[64][72];
    __shared__ bf16 Vs[64][72];       // [h][sigma-permuted s-slot]

    const int tid = threadIdx.x, wave = tid >> 6, lane = tid & 63;
    const int lr = lane & 15, lk = (lane >> 4) * 8;
    const int qsel = (lane >> 4) << 2;
    const int id = xcd_swz(blockIdx.y * gridDim.x + blockIdx.x, 512);
    const int qt2 = id & 15, z = id >> 4;
    const int qtile = qt2 * 2 + (wave >> 2);
    const int wq4 = wave & 3;
    const bf16* qb = q + ((size_t)z * 2048 + qtile * 64) * 64;
    const bf16* kb = k + (size_t)z * 2048 * 64;
    const bf16* vb = vt + (size_t)z * 64 * 2048;

    const int sr = tid >> 3, so = (tid & 7) * 8;
    const int vb0 = (so & 32) + ((so >> 4) & 1) * 4 + ((so >> 3) & 1) * 16;

    union V8 { bf16x8 v; bf16x4 h[2]; };
    bf16x8 kr0;
    V8 vr0;
    auto load_tile = [&](int st) {
        kr0 = *(const bf16x8*)&kb[(size_t)(st * 64 + sr) * 64 + so];
        vr0.v = *(const bf16x8*)&vb[(size_t)sr * 2048 + st * 64 + so];
    };
    auto write_tile = [&]() {
        *(bf16x8*)&Ks[sr][so]     = kr0;
        *(bf16x4*)&Vs[sr][vb0]     = vr0.h[0];
        *(bf16x4*)&Vs[sr][vb0 + 8] = vr0.h[1];
    };

    load_tile(0);
    write_tile();
    const bf16x8 aq0 = *(const bf16x8*)&qb[(wq4 * 16 + lr) * 64 + lk];
    const bf16x8 aq1 = *(const bf16x8*)&qb[(wq4 * 16 + lr) * 64 + 32 + lk];
    __syncthreads();

    bf16x8 ones;
    #pragma unroll
    for (int i = 0; i < 8; ++i) ones[i] = (bf16)1.0f;

    f32x4 accO[4] = {};
    f32x4 accL = {};

    for (int kt = 0; kt < 32; ++kt) {
        if (kt < 31) load_tile(kt + 1);

        f32x4 p4[4] = {};
        __builtin_amdgcn_s_setprio(1);
        #pragma unroll
        for (int j = 0; j < 4; ++j) {
            p4[j] = MFMA16(*(const bf16x8*)&Ks[j * 16 + lr][lk],      aq0, p4[j], 0, 0, 0);
            p4[j] = MFMA16(*(const bf16x8*)&Ks[j * 16 + lr][32 + lk], aq1, p4[j], 0, 0, 0);
        }
        __builtin_amdgcn_s_setprio(0);

        // fixed-m softmax: P = 2^s directly (no max tracking, no subtract)
        #pragma unroll
        for (int j = 0; j < 4; ++j)
            #pragma unroll
            for (int r = 0; r < 4; ++r)
                p4[j][r] = fexp2(p4[j][r]);

        union FW { unsigned u[4]; bf16x8 v; } f0, f1;
        f0.u[0] = pk2(p4[0][0], p4[0][1]);
        f0.u[1] = pk2(p4[0][2], p4[0][3]);
        f0.u[2] = pk2(p4[1][0], p4[1][1]);
        f0.u[3] = pk2(p4[1][2], p4[1][3]);
        f1.u[0] = pk2(p4[2][0], p4[2][1]);
        f1.u[1] = pk2(p4[2][2], p4[2][3]);
        f1.u[2] = pk2(p4[3][0], p4[3][1]);
        f1.u[3] = pk2(p4[3][2], p4[3][3]);

        __builtin_amdgcn_s_setprio(1);
        #pragma unroll
        for (int nh = 0; nh < 4; ++nh) {
            accO[nh] = MFMA16(f0.v, *(const bf16x8*)&Vs[nh * 16 + lr][lk],      accO[nh], 0, 0, 0);
            accO[nh] = MFMA16(f1.v, *(const bf16x8*)&Vs[nh * 16 + lr][32 + lk], accO[nh], 0, 0, 0);
        }
        accL = MFMA16(f0.v, ones, accL, 0, 0, 0);
        accL = MFMA16(f1.v, ones, accL, 0, 0, 0);
        __builtin_amdgcn_s_setprio(0);

        __syncthreads();
        if (kt < 31) write_tile();
        __syncthreads();
    }

    const int bb = z >> 4, nn = z & 15;
    #pragma unroll
    for (int nh = 0; nh < 4; ++nh)
        #pragma unroll
        for (int r = 0; r < 4; ++r) {
            const int t = qtile * 64 + wq4 * 16 + qsel + r;
            const int hh = nh * 16 + lr;
            enc[((size_t)(bb * 2048 + t)) * 1024 + nn * 64 + hh] =
                (bf16)(accO[nh][r] / accL[r]);
        }
}

// ---------------------------------------------------------------------------
extern "C" void kernel_launch(void* const* d_in, const int* in_sizes, int n_in,
                              void* d_out, int out_size, void* d_ws, size_t ws_size,
                              hipStream_t stream) {
    const float* x    = (const float*)d_in[0];
    const float* ln0s = (const float*)d_in[1];
    const float* ln0b = (const float*)d_in[2];
    const float* ln1s = (const float*)d_in[3];
    const float* ln1b = (const float*)d_in[4];
    const float* wq   = (const float*)d_in[5];
    const float* bq   = (const float*)d_in[6];
    const float* wk   = (const float*)d_in[7];
    const float* bk   = (const float*)d_in[8];
    const float* wv   = (const float*)d_in[9];
    const float* bv   = (const float*)d_in[10];
    const float* wo   = (const float*)d_in[11];
    const float* bo   = (const float*)d_in[12];
    const float* w0   = (const float*)d_in[13];
    const float* b0   = (const float*)d_in[14];
    const float* w1   = (const float*)d_in[15];
    const float* b1   = (const float*)d_in[16];
    float* out = (float*)d_out;

    // workspace layout (128 MiB)
    char* p = (char*)d_ws;
    bf16* Wqkv = (bf16*)p; p += (size_t)3072 * 1024 * 2;
    bf16* Wot  = (bf16*)p; p += (size_t)1024 * 1024 * 2;
    bf16* W0t  = (bf16*)p; p += (size_t)4096 * 1024 * 2;
    bf16* W1t  = (bf16*)p; p += (size_t)1024 * 4096 * 2;
    bf16* y0   = (bf16*)p; p += (size_t)4096 * 1024 * 2;
    bf16* qbuf = (bf16*)p; p += (size_t)4096 * 1024 * 2;
    bf16* kbuf = (bf16*)p; p += (size_t)4096 * 1024 * 2;
    bf16* vbuf = (bf16*)p; p += (size_t)4096 * 1024 * 2;
    bf16* vtb  = (bf16*)p; p += (size_t)4096 * 1024 * 2;
    bf16* enc  = (bf16*)p; p += (size_t)4096 * 1024 * 2;
    float* x1  = (float*)p; p += (size_t)4096 * 1024 * 4;
    bf16* y1   = (bf16*)p; p += (size_t)4096 * 1024 * 2;
    bf16* h    = (bf16*)p; p += (size_t)4096 * 4096 * 2;

    const dim3 tb(32, 8);
    transpose_all<<<12288, tb, 0, stream>>>(wq, wk, wv, wo, w0, w1,
                                            Wqkv, Wot, W0t, W1t);

    ln_kernel<<<4096, 256, 0, stream>>>(x, ln0s, ln0b, y0);

    // fused QKV projection (K=1024): single-buffer 64x64, 3072 wg
    gemm_kernel<0, 64, 64, 4, false><<<dim3(48, 64), 256, 0, stream>>>(
        y0, Wqkv, 4096, 3072, 1024, bq, bk, bv, nullptr, qbuf, kbuf, vbuf, nullptr);

    transpose_v<<<dim3(2, 64, 32), tb, 0, stream>>>(vbuf, vtb);

    // attention: 512 blocks x 8 waves (2 Q-tiles/block, shared K/V staging)
    attn_kernel<<<dim3(16, 32), 512, 0, stream>>>(qbuf, kbuf, vtb, enc);

    // out projection + residual (K=1024): single-buffer 64x64, 1024 wg
    gemm_kernel<1, 64, 64, 4, false><<<dim3(16, 64), 256, 0, stream>>>(
        enc, Wot, 4096, 1024, 1024, bo, nullptr, nullptr, x, nullptr, nullptr, nullptr, x1);

    ln_kernel<<<4096, 256, 0, stream>>>(x1, ln1s, ln1b, y1);

    // MLP up + GELU (K=1024): single-buffer 64x64, 4096 wg
    gemm_kernel<2, 64, 64, 4, false><<<dim3(64, 64), 256, 0, stream>>>(
        y1, W0t, 4096, 4096, 1024, b0, nullptr, nullptr, nullptr, h, nullptr, nullptr, nullptr);

    // MLP down + bias + residual (K=4096): single-buffer 64x64, 1024 wg
    gemm_kernel<1, 64, 64, 4, false><<<dim3(16, 64), 256, 0, stream>>>(
        h, W1t, 4096, 1024, 4096, b1, nullptr, nullptr, x1, nullptr, nullptr, nullptr, out);
}

// Round 23
// 211.191 us; speedup vs baseline: 1.2217x; 1.2217x over previous
//
#include <hip/hip_runtime.h>
#include <cstdint>
#include <cstddef>

typedef __bf16 bf16;
typedef __attribute__((ext_vector_type(8))) __bf16 bf16x8;
typedef __attribute__((ext_vector_type(4))) __bf16 bf16x4;
typedef __attribute__((ext_vector_type(4))) float f32x4;

#define MFMA16 __builtin_amdgcn_mfma_f32_16x16x32_bf16

// async global -> LDS, 16B per lane. LDS dest is base + lane*16.
__device__ __forceinline__ void gload16(const bf16* g, bf16* l) {
    __builtin_amdgcn_global_load_lds(
        (const __attribute__((address_space(1))) uint32_t*)g,
        (__attribute__((address_space(3))) uint32_t*)l, 16, 0, 0);
}

// pack two f32 -> u32 of 2 bf16 (elem0 = lo bits)
__device__ __forceinline__ unsigned pk2(float lo, float hi) {
    union { bf16 h[2]; unsigned u; } c;
    c.h[0] = (bf16)lo; c.h[1] = (bf16)hi;
    return c.u;
}
// raw v_exp_f32: 2^x
__device__ __forceinline__ float fexp2(float x) {
    float r;
    asm("v_exp_f32 %0, %1" : "=v"(r) : "v"(x));
    return r;
}

// bijective XCD chunk swizzle (nwg % 8 == 0)
__device__ __forceinline__ int xcd_swz(int id, int nwg) {
    return (id & 7) * (nwg >> 3) + (id >> 3);
}

#define SBAR()  __builtin_amdgcn_s_barrier()
#define SCHED() __builtin_amdgcn_sched_barrier(0)

// ---------------------------------------------------------------------------
// Fused weight prep: all 6 transposes+casts in ONE launch.
// ---------------------------------------------------------------------------
__global__ __launch_bounds__(256) void transpose_all(
    const float* __restrict__ wq, const float* __restrict__ wk,
    const float* __restrict__ wv, const float* __restrict__ wo,
    const float* __restrict__ w0, const float* __restrict__ w1,
    bf16* __restrict__ Wqkv, bf16* __restrict__ Wot,
    bf16* __restrict__ W0t, bf16* __restrict__ W1t)
{
    __shared__ float t[32][33];
    const int b = blockIdx.x;
    const float* src;
    bf16* dst;
    int K, N, tt;
    if (b < 1024)      { src = wq; dst = Wqkv;                       K = 1024; N = 1024; tt = b; }
    else if (b < 2048) { src = wk; dst = Wqkv + (size_t)1024 * 1024; K = 1024; N = 1024; tt = b - 1024; }
    else if (b < 3072) { src = wv; dst = Wqkv + (size_t)2048 * 1024; K = 1024; N = 1024; tt = b - 2048; }
    else if (b < 4096) { src = wo; dst = Wot;                        K = 1024; N = 1024; tt = b - 3072; }
    else if (b < 8192) { src = w0; dst = W0t;                        K = 1024; N = 4096; tt = b - 4096; }
    else               { src = w1; dst = W1t;                        K = 4096; N = 1024; tt = b - 8192; }
    const int ntx = N >> 5;
    const int n0 = (tt % ntx) * 32, k0 = (tt / ntx) * 32;
    const int tx = threadIdx.x, ty = threadIdx.y;
    #pragma unroll
    for (int i = ty; i < 32; i += 8)
        t[i][tx] = src[(size_t)(k0 + i) * N + n0 + tx];
    __syncthreads();
    #pragma unroll
    for (int i = ty; i < 32; i += 8)
        dst[(size_t)(n0 + i) * K + k0 + tx] = (bf16)t[tx][i];
}

// ---------------------------------------------------------------------------
// Batched bf16 transpose for V: src [Z][2048][64] -> dst [Z][64][2048]
// ---------------------------------------------------------------------------
__global__ __launch_bounds__(256) void transpose_v(
    const bf16* __restrict__ src, bf16* __restrict__ dst)
{
    __shared__ bf16 t[32][33];
    const int z = blockIdx.z;
    const int h0 = blockIdx.x * 32, s0 = blockIdx.y * 32;
    const bf16* sp = src + (size_t)z * 2048 * 64;
    bf16* dp = dst + (size_t)z * 64 * 2048;
    const int tx = threadIdx.x, ty = threadIdx.y;
    #pragma unroll
    for (int i = ty; i < 32; i += 8)
        t[i][tx] = sp[(size_t)(s0 + i) * 64 + h0 + tx];
    __syncthreads();
    #pragma unroll
    for (int i = ty; i < 32; i += 8)
        dp[(size_t)(h0 + i) * 2048 + s0 + tx] = t[tx][i];
}

// ---------------------------------------------------------------------------
// LayerNorm (D=1024) fp32 in -> bf16 out. One block (256 thr) per row.
// ---------------------------------------------------------------------------
__global__ __launch_bounds__(256) void ln_kernel(
    const float* __restrict__ x, const float* __restrict__ sc,
    const float* __restrict__ bi, bf16* __restrict__ y)
{
    const int row = blockIdx.x, tid = threadIdx.x;
    const f32x4 v = ((const f32x4*)(x + (size_t)row * 1024))[tid];
    float s  = v[0] + v[1] + v[2] + v[3];
    float s2 = v[0]*v[0] + v[1]*v[1] + v[2]*v[2] + v[3]*v[3];
    #pragma unroll
    for (int d = 1; d < 64; d <<= 1) {
        s  += __shfl_xor(s, d);
        s2 += __shfl_xor(s2, d);
    }
    __shared__ float red[8];
    if ((tid & 63) == 0) { red[tid >> 6] = s; red[4 + (tid >> 6)] = s2; }
    __syncthreads();
    s  = red[0] + red[1] + red[2] + red[3];
    s2 = red[4] + red[5] + red[6] + red[7];
    const float mu = s * (1.f / 1024.f);
    const float rstd = rsqrtf(s2 * (1.f / 1024.f) - mu * mu + 1e-6f);
    const f32x4 s4 = ((const f32x4*)sc)[tid];
    const f32x4 b4 = ((const f32x4*)bi)[tid];
    bf16x4 o;
    #pragma unroll
    for (int j = 0; j < 4; ++j)
        o[j] = (bf16)((v[j] - mu) * rstd * s4[j] + b4[j]);
    ((bf16x4*)(y + (size_t)row * 1024))[tid] = o;
}

// ---------------------------------------------------------------------------
// bf16 GEMM (R20/R21-validated), BK=64, 3-bit both-sides XOR swizzle:
//  DBUF=false: SINGLE-buffered LDS + TLP. DBUF=true: dbuf + counted vmcnt.
// Tiles: 128x128 (32KB, for big-N GEMMs: L3-friendly arithmetic intensity),
//        64x64 (16KB, for N=1024 GEMMs: 4 blocks/CU without refetch blowup).
// EPI 0: QKV scatter (+bias; Q pre-scaled by 0.125*log2e), [Z][T][H] x3.
// EPI 1: fp32 out = acc + bias + res. EPI 2: bf16 gelu(acc + bias).
// ---------------------------------------------------------------------------
template <int EPI, int BM, int BN, int NW, bool DBUF>
__global__ __launch_bounds__(NW * 64, 2) void gemm_kernel(
    const bf16* __restrict__ A, const bf16* __restrict__ Bt,
    int M, int N, int K,
    const float* __restrict__ b0, const float* __restrict__ b1,
    const float* __restrict__ b2, const float* __restrict__ res,
    bf16* __restrict__ o0, bf16* __restrict__ o1, bf16* __restrict__ o2,
    float* __restrict__ of)
{
    constexpr int NRW    = NW / 2;
    constexpr int MR     = BM / 32;
    constexpr int NR     = BN / 16 / NRW;
    constexpr int ACALLS = BM / (8 * NW);
    constexpr int BCALLS = BN / (8 * NW);
    constexpr int NLOADS = ACALLS + BCALLS;
    constexpr int NBUF   = DBUF ? 2 : 1;
    static_assert(NLOADS == 8 || NLOADS == 6 || NLOADS == 4, "vmcnt literal");
    __shared__ bf16 As[NBUF][BM * 64];
    __shared__ bf16 Bs[NBUF][BN * 64];

    const int tid = threadIdx.x;
    const int wave = tid >> 6, lane = tid & 63;
    const int wr = (wave / NRW) * (MR * 16), wc = (wave % NRW) * (NR * 16);
    const int lr = lane & 15, lg = lane >> 4;

    const int nwg = gridDim.x * gridDim.y;
    const int id = xcd_swz(blockIdx.y * gridDim.x + blockIdx.x, nwg);
    const int bm = (id / gridDim.x) * BM, bn = (id % gridDim.x) * BN;

    f32x4 acc[MR][NR] = {};

    const int srow = tid >> 3;
    const int scol = (((tid & 7) ^ ((tid >> 3) & 7)) * 8);
    const bf16* Ag = A  + (size_t)(bm + srow) * K + scol;
    const bf16* Bg = Bt + (size_t)(bn + srow) * K + scol;

    auto stage = [&](int buf, int k0) {
        #pragma unroll
        for (int c = 0; c < ACALLS; ++c)
            gload16(Ag + (size_t)(c * 8 * NW) * K + k0,
                    &As[buf][(c * 8 * NW) * 64] + (size_t)tid * 8);
        #pragma unroll
        for (int c = 0; c < BCALLS; ++c)
            gload16(Bg + (size_t)(c * 8 * NW) * K + k0,
                    &Bs[buf][(c * 8 * NW) * 64] + (size_t)tid * 8);
    };

    const int f3 = lane & 7;
    const int ko0 = ((0 + lg) ^ f3) * 8;     // kh = 0
    const int ko1 = ((4 + lg) ^ f3) * 8;     // kh = 1

    auto mfma_tile = [&](int buf) {
        #pragma unroll
        for (int kh = 0; kh < 2; ++kh) {
            const int ko = kh ? ko1 : ko0;
            bf16x8 a[MR], b[NR];
            #pragma unroll
            for (int m = 0; m < MR; ++m)
                a[m] = *(const bf16x8*)&As[buf][(wr + m * 16 + lr) * 64 + ko];
            #pragma unroll
            for (int n = 0; n < NR; ++n)
                b[n] = *(const bf16x8*)&Bs[buf][(wc + n * 16 + lr) * 64 + ko];
            #pragma unroll
            for (int m = 0; m < MR; ++m)
                #pragma unroll
                for (int n = 0; n < NR; ++n)
                    acc[m][n] = MFMA16(a[m], b[n], acc[m][n], 0, 0, 0);
        }
    };

    const int nk = K >> 6;
    if constexpr (!DBUF) {
        for (int i = 0; i < nk; ++i) {
            stage(0, i << 6);
            __syncthreads();
            mfma_tile(0);
            __syncthreads();
        }
    } else {
        stage(0, 0);
        __syncthreads();
        int cur = 0;
        for (int i = 0; i < nk; ++i) {
            if (i + 1 < nk) {
                stage(cur ^ 1, (i + 1) << 6);
                SCHED();
                if constexpr (NLOADS == 8)
                    asm volatile("s_waitcnt vmcnt(8)" ::: "memory");
                else if constexpr (NLOADS == 6)
                    asm volatile("s_waitcnt vmcnt(6)" ::: "memory");
                else
                    asm volatile("s_waitcnt vmcnt(4)" ::: "memory");
            } else {
                asm volatile("s_waitcnt vmcnt(0)" ::: "memory");
            }
            SCHED();
            SBAR();
            SCHED();
            mfma_tile(cur);
            SCHED();
            asm volatile("s_waitcnt lgkmcnt(0)" ::: "memory");
            SCHED();
            SBAR();
            SCHED();
            cur ^= 1;
        }
    }

    const int rbase = bm + wr + (lg << 2);
    const int cbase = bn + wc + lr;
    #pragma unroll
    for (int m = 0; m < MR; ++m) {
        #pragma unroll
        for (int n = 0; n < NR; ++n) {
            const f32x4 v = acc[m][n];
            #pragma unroll
            for (int r = 0; r < 4; ++r) {
                const int row = rbase + m * 16 + r;
                const int col = cbase + n * 16;
                const float val = v[r];
                if constexpr (EPI == 0) {
                    const int which = col >> 10, cc = col & 1023;
                    const float* bp = (which == 0) ? b0 : (which == 1) ? b1 : b2;
                    bf16* dp = (which == 0) ? o0 : (which == 1) ? o1 : o2;
                    const float scl = (which == 0) ? 0.18033688011112042f : 1.0f;
                    const int bb = row >> 11, t = row & 2047;
                    const int nh = cc >> 6, hh = cc & 63;
                    dp[(((size_t)(bb * 16 + nh) * 2048 + t) << 6) + hh] =
                        (bf16)((val + bp[cc]) * scl);
                } else if constexpr (EPI == 1) {
                    of[(size_t)row * N + col] =
                        val + b0[col] + res[(size_t)row * N + col];
                } else {
                    const float xg = val + b0[col];
                    const float z2 = 1.5957691216f * (xg + 0.044715f * xg * xg * xg);
                    o0[(size_t)row * N + col] = (bf16)(xg / (1.f + __expf(-z2)));
                }
            }
        }
    }
}

// ---------------------------------------------------------------------------
// Flash attention (R21-validated, unchanged): fixed-m softmax (P = 2^s,
// no max tracking -- exp2-domain scores bounded ~2^26, scale cancels in
// O/l), 8 waves / 2 Q-tiles per block, shared K/V staging, swapped-QK^T,
// sigma-permuted V, l-via-ones-MFMA, direct-Q. Grid: 512 blocks.
// ---------------------------------------------------------------------------
__global__ __launch_bounds__(512) void attn_kernel(
    const bf16* __restrict__ q, const bf16* __restrict__ k,
    const bf16* __restrict__ vt, bf16* __restrict__ enc)
{
    __shared__ bf16 Ks[64][72];
    __shared__ bf16 Vs[64][72];       // [h][sigma-permuted s-slot]

    const int tid = threadIdx.x, wave = tid >> 6, lane = tid & 63;
    const int lr = lane & 15, lk = (lane >> 4) * 8;
    const int qsel = (lane >> 4) << 2;
    const int id = xcd_swz(blockIdx.y * gridDim.x + blockIdx.x, 512);
    const int qt2 = id & 15, z = id >> 4;
    const int qtile = qt2 * 2 + (wave >> 2);
    const int wq4 = wave & 3;
    const bf16* qb = q + ((size_t)z * 2048 + qtile * 64) * 64;
    const bf16* kb = k + (size_t)z * 2048 * 64;
    const bf16* vb = vt + (size_t)z * 64 * 2048;

    const int sr = tid >> 3, so = (tid & 7) * 8;
    const int vb0 = (so & 32) + ((so >> 4) & 1) * 4 + ((so >> 3) & 1) * 16;

    union V8 { bf16x8 v; bf16x4 h[2]; };
    bf16x8 kr0;
    V8 vr0;
    auto load_tile = [&](int st) {
        kr0 = *(const bf16x8*)&kb[(size_t)(st * 64 + sr) * 64 + so];
        vr0.v = *(const bf16x8*)&vb[(size_t)sr * 2048 + st * 64 + so];
    };
    auto write_tile = [&]() {
        *(bf16x8*)&Ks[sr][so]     = kr0;
        *(bf16x4*)&Vs[sr][vb0]     = vr0.h[0];
        *(bf16x4*)&Vs[sr][vb0 + 8] = vr0.h[1];
    };

    load_tile(0);
    write_tile();
    const bf16x8 aq0 = *(const bf16x8*)&qb[(wq4 * 16 + lr) * 64 + lk];
    const bf16x8 aq1 = *(const bf16x8*)&qb[(wq4 * 16 + lr) * 64 + 32 + lk];
    __syncthreads();

    bf16x8 ones;
    #pragma unroll
    for (int i = 0; i < 8; ++i) ones[i] = (bf16)1.0f;

    f32x4 accO[4] = {};
    f32x4 accL = {};

    for (int kt = 0; kt < 32; ++kt) {
        if (kt < 31) load_tile(kt + 1);

        f32x4 p4[4] = {};
        __builtin_amdgcn_s_setprio(1);
        #pragma unroll
        for (int j = 0; j < 4; ++j) {
            p4[j] = MFMA16(*(const bf16x8*)&Ks[j * 16 + lr][lk],      aq0, p4[j], 0, 0, 0);
            p4[j] = MFMA16(*(const bf16x8*)&Ks[j * 16 + lr][32 + lk], aq1, p4[j], 0, 0, 0);
        }
        __builtin_amdgcn_s_setprio(0);

        // fixed-m softmax: P = 2^s directly (no max tracking, no subtract)
        #pragma unroll
        for (int j = 0; j < 4; ++j)
            #pragma unroll
            for (int r = 0; r < 4; ++r)
                p4[j][r] = fexp2(p4[j][r]);

        union FW { unsigned u[4]; bf16x8 v; } f0, f1;
        f0.u[0] = pk2(p4[0][0], p4[0][1]);
        f0.u[1] = pk2(p4[0][2], p4[0][3]);
        f0.u[2] = pk2(p4[1][0], p4[1][1]);
        f0.u[3] = pk2(p4[1][2], p4[1][3]);
        f1.u[0] = pk2(p4[2][0], p4[2][1]);
        f1.u[1] = pk2(p4[2][2], p4[2][3]);
        f1.u[2] = pk2(p4[3][0], p4[3][1]);
        f1.u[3] = pk2(p4[3][2], p4[3][3]);

        __builtin_amdgcn_s_setprio(1);
        #pragma unroll
        for (int nh = 0; nh < 4; ++nh) {
            accO[nh] = MFMA16(f0.v, *(const bf16x8*)&Vs[nh * 16 + lr][lk],      accO[nh], 0, 0, 0);
            accO[nh] = MFMA16(f1.v, *(const bf16x8*)&Vs[nh * 16 + lr][32 + lk], accO[nh], 0, 0, 0);
        }
        accL = MFMA16(f0.v, ones, accL, 0, 0, 0);
        accL = MFMA16(f1.v, ones, accL, 0, 0, 0);
        __builtin_amdgcn_s_setprio(0);

        __syncthreads();
        if (kt < 31) write_tile();
        __syncthreads();
    }

    const int bb = z >> 4, nn = z & 15;
    #pragma unroll
    for (int nh = 0; nh < 4; ++nh)
        #pragma unroll
        for (int r = 0; r < 4; ++r) {
            const int t = qtile * 64 + wq4 * 16 + qsel + r;
            const int hh = nh * 16 + lr;
            enc[((size_t)(bb * 2048 + t)) * 1024 + nn * 64 + hh] =
                (bf16)(accO[nh][r] / accL[r]);
        }
}

// ---------------------------------------------------------------------------
extern "C" void kernel_launch(void* const* d_in, const int* in_sizes, int n_in,
                              void* d_out, int out_size, void* d_ws, size_t ws_size,
                              hipStream_t stream) {
    const float* x    = (const float*)d_in[0];
    const float* ln0s = (const float*)d_in[1];
    const float* ln0b = (const float*)d_in[2];
    const float* ln1s = (const float*)d_in[3];
    const float* ln1b = (const float*)d_in[4];
    const float* wq   = (const float*)d_in[5];
    const float* bq   = (const float*)d_in[6];
    const float* wk   = (const float*)d_in[7];
    const float* bk   = (const float*)d_in[8];
    const float* wv   = (const float*)d_in[9];
    const float* bv   = (const float*)d_in[10];
    const float* wo   = (const float*)d_in[11];
    const float* bo   = (const float*)d_in[12];
    const float* w0   = (const float*)d_in[13];
    const float* b0   = (const float*)d_in[14];
    const float* w1   = (const float*)d_in[15];
    const float* b1   = (const float*)d_in[16];
    float* out = (float*)d_out;

    // workspace layout (128 MiB)
    char* p = (char*)d_ws;
    bf16* Wqkv = (bf16*)p; p += (size_t)3072 * 1024 * 2;
    bf16* Wot  = (bf16*)p; p += (size_t)1024 * 1024 * 2;
    bf16* W0t  = (bf16*)p; p += (size_t)4096 * 1024 * 2;
    bf16* W1t  = (bf16*)p; p += (size_t)1024 * 4096 * 2;
    bf16* y0   = (bf16*)p; p += (size_t)4096 * 1024 * 2;
    bf16* qbuf = (bf16*)p; p += (size_t)4096 * 1024 * 2;
    bf16* kbuf = (bf16*)p; p += (size_t)4096 * 1024 * 2;
    bf16* vbuf = (bf16*)p; p += (size_t)4096 * 1024 * 2;
    bf16* vtb  = (bf16*)p; p += (size_t)4096 * 1024 * 2;
    bf16* enc  = (bf16*)p; p += (size_t)4096 * 1024 * 2;
    float* x1  = (float*)p; p += (size_t)4096 * 1024 * 4;
    bf16* y1   = (bf16*)p; p += (size_t)4096 * 1024 * 2;
    bf16* h    = (bf16*)p; p += (size_t)4096 * 4096 * 2;

    const dim3 tb(32, 8);
    transpose_all<<<12288, tb, 0, stream>>>(wq, wk, wv, wo, w0, w1,
                                            Wqkv, Wot, W0t, W1t);

    ln_kernel<<<4096, 256, 0, stream>>>(x, ln0s, ln0b, y0);

    // fused QKV projection (K=1024): single-buffer 128x128
    gemm_kernel<0, 128, 128, 4, false><<<dim3(24, 32), 256, 0, stream>>>(
        y0, Wqkv, 4096, 3072, 1024, bq, bk, bv, nullptr, qbuf, kbuf, vbuf, nullptr);

    transpose_v<<<dim3(2, 64, 32), tb, 0, stream>>>(vbuf, vtb);

    // attention: 512 blocks x 8 waves (2 Q-tiles/block, shared K/V staging)
    attn_kernel<<<dim3(16, 32), 512, 0, stream>>>(qbuf, kbuf, vtb, enc);

    // out projection + residual (K=1024): single-buffer 64x64, 1024 wg
    gemm_kernel<1, 64, 64, 4, false><<<dim3(16, 64), 256, 0, stream>>>(
        enc, Wot, 4096, 1024, 1024, bo, nullptr, nullptr, x, nullptr, nullptr, nullptr, x1);

    ln_kernel<<<4096, 256, 0, stream>>>(x1, ln1s, ln1b, y1);

    // MLP up + GELU (K=1024): single-buffer 128x128
    gemm_kernel<2, 128, 128, 4, false><<<dim3(32, 32), 256, 0, stream>>>(
        y1, W0t, 4096, 4096, 1024, b0, nullptr, nullptr, nullptr, h, nullptr, nullptr, nullptr);

    // MLP down + bias + residual (K=4096): single-buffer 64x64, 1024 wg
    gemm_kernel<1, 64, 64, 4, false><<<dim3(16, 64), 256, 0, stream>>>(
        h, W1t, 4096, 1024, 4096, b1, nullptr, nullptr, x1, nullptr, nullptr, nullptr, out);
}